// Round 5
// baseline (650.315 us; speedup 1.0000x reference)
//
#include <hip/hip_runtime.h>
#include <hip/hip_bf16.h>
#include <stdint.h>

typedef __hip_bfloat16 bf16;
typedef __attribute__((ext_vector_type(8))) short bv8;    // 8 x bf16 (mfma A/B frag)
typedef __attribute__((ext_vector_type(4))) float f32x4;  // mfma C/D frag

// Problem constants: B=2, T=1024, S_ENC=1024, D=2048, NQ=16, NKV=8, H=256, SKV=2048

__device__ __forceinline__ f32x4 mfma16(bv8 a, bv8 b, f32x4 c) {
  return __builtin_amdgcn_mfma_f32_16x16x32_bf16(a, b, c, 0, 0, 0);
}

__device__ __forceinline__ void gload16(const void* g, void* lds) {
  __builtin_amdgcn_global_load_lds((const __attribute__((address_space(1))) void*)g,
                                   (__attribute__((address_space(3))) void*)lds, 16, 0, 0);
}

__device__ __forceinline__ void storeC(float* p, float v) { *p = v; }
__device__ __forceinline__ void storeC(bf16* p, float v) { *p = __float2bfloat16(v); }

// ---------------- elementwise f32 -> bf16 ----------------
__global__ void cast_f32_bf16(const float* __restrict__ src, bf16* __restrict__ dst, int n4) {
  int i = blockIdx.x * blockDim.x + threadIdx.x;
  if (i >= n4) return;
  float4 v = reinterpret_cast<const float4*>(src)[i];
  bf16 t[4] = {__float2bfloat16(v.x), __float2bfloat16(v.y),
               __float2bfloat16(v.z), __float2bfloat16(v.w)};
  reinterpret_cast<uint64_t*>(dst)[i] = *reinterpret_cast<uint64_t*>(t);
}

// ------- batched transpose+cast: src f32 [z][R][C] -> dst bf16 [z][C][R] -------
__global__ void transpose_cast(const float* __restrict__ src, bf16* __restrict__ dst,
                               int R, int C) {
  __shared__ float tile[32][33];
  const int z = blockIdx.z;
  const float* s = src + (size_t)z * R * C;
  bf16* d = dst + (size_t)z * R * C;
  const int c0 = blockIdx.x * 32, r0 = blockIdx.y * 32;
  const int x = threadIdx.x, y = threadIdx.y;
#pragma unroll
  for (int i = 0; i < 32; i += 8)
    tile[y + i][x] = s[(size_t)(r0 + y + i) * C + c0 + x];
  __syncthreads();
#pragma unroll
  for (int i = 0; i < 32; i += 8)
    d[(size_t)(c0 + y + i) * R + r0 + x] = __float2bfloat16(tile[x][y + i]);
}

// ------- V transpose (bf16 in): per (b,kvh): [1024 t][256 h] -> vt [256 h][2048 s] -------
__global__ void transpose_v(const bf16* __restrict__ src, int src_ld,
                            bf16* __restrict__ dst, int t0) {
  __shared__ bf16 tile[32][33];
  const int z = blockIdx.z, b = z >> 3, kvh = z & 7;
  const bf16* s = src + (size_t)(b * 1024) * src_ld + kvh * 256;
  bf16* d = dst + (size_t)(z * 256) * 2048 + t0;
  const int h0 = blockIdx.x * 32, tt0 = blockIdx.y * 32;
  const int x = threadIdx.x, y = threadIdx.y;
#pragma unroll
  for (int i = 0; i < 32; i += 8)
    tile[y + i][x] = s[(size_t)(tt0 + y + i) * src_ld + h0 + x];
  __syncthreads();
#pragma unroll
  for (int i = 0; i < 32; i += 8)
    d[(size_t)(h0 + y + i) * 2048 + tt0 + x] = tile[x][y + i];
}

// ---------------- GEMM: C[M][N] = A[M][K] * Bt[N][K]^T  (m97-style 128x128, BK=32) ----------------
template <typename CT>
__launch_bounds__(256)
__global__ void gemm_bt(const bf16* __restrict__ A, const bf16* __restrict__ Bt,
                        CT* __restrict__ C, int N, int K) {
  __shared__ __align__(16) bf16 As[128 * 32];
  __shared__ __align__(16) bf16 Bs[128 * 32];
  const int tid = threadIdx.x;
  const int w = tid >> 6, l = tid & 63;
  const int wr = w >> 1, wc = w & 1;
  const int l15 = l & 15, lhi = l >> 4;
  const int m0 = blockIdx.y * 128, n0 = blockIdx.x * 128;
  const bf16* ag = A + (size_t)(m0 + (tid >> 2)) * K + (tid & 3) * 8;
  const bf16* bg = Bt + (size_t)(n0 + (tid >> 2)) * K + (tid & 3) * 8;
  bf16* asw = As + w * 512;
  bf16* bsw = Bs + w * 512;
  f32x4 acc[4][4] = {};
  for (int k0 = 0; k0 < K; k0 += 32) {
    gload16(ag + k0, asw);
    gload16(ag + (size_t)64 * K + k0, asw + 2048);
    gload16(bg + k0, bsw);
    gload16(bg + (size_t)64 * K + k0, bsw + 2048);
    asm volatile("s_waitcnt vmcnt(0)" ::: "memory");
    __syncthreads();
    bv8 af[4], bfv[4];
#pragma unroll
    for (int m = 0; m < 4; ++m)
      af[m] = *reinterpret_cast<const bv8*>(As + (wr * 64 + m * 16 + l15) * 32 + lhi * 8);
#pragma unroll
    for (int n = 0; n < 4; ++n)
      bfv[n] = *reinterpret_cast<const bv8*>(Bs + (wc * 64 + n * 16 + l15) * 32 + lhi * 8);
#pragma unroll
    for (int m = 0; m < 4; ++m)
#pragma unroll
      for (int n = 0; n < 4; ++n)
        acc[m][n] = mfma16(af[m], bfv[n], acc[m][n]);
    __syncthreads();
  }
  const int r0 = m0 + wr * 64 + lhi * 4;
  const int c0 = n0 + wc * 64 + l15;
#pragma unroll
  for (int m = 0; m < 4; ++m)
#pragma unroll
    for (int n = 0; n < 4; ++n) {
      f32x4 v = acc[m][n];
#pragma unroll
      for (int j = 0; j < 4; ++j)
        storeC(&C[(size_t)(r0 + m * 16 + j) * N + c0 + n * 16], v[j]);
    }
}

// ---------------- RMSNorm (+optional RoPE) + scale ----------------
template <bool ROPE>
__launch_bounds__(256)
__global__ void norm_finalize(const bf16* __restrict__ src, int src_ld, int src_col0,
                              const float* __restrict__ scale,
                              const int* __restrict__ pos_ids,
                              bf16* __restrict__ dst, int nheads, int dst_S, int dst_t0,
                              float mul) {
  const int gid = blockIdx.x * 4 + (threadIdx.x >> 6);
  const int l = threadIdx.x & 63;
  const int token = gid / nheads;
  const int n = gid - token * nheads;
  const int b = token >> 10;
  const int t = token & 1023;
  const size_t soff = (size_t)token * src_ld + src_col0 + n * 256 + l * 4;
  bf16 xb[4];
  *reinterpret_cast<uint64_t*>(xb) = *reinterpret_cast<const uint64_t*>(src + soff);
  float x[4];
#pragma unroll
  for (int c = 0; c < 4; ++c) x[c] = __bfloat162float(xb[c]);
  float ss = x[0] * x[0] + x[1] * x[1] + x[2] * x[2] + x[3] * x[3];
#pragma unroll
  for (int d = 1; d < 64; d <<= 1) ss += __shfl_xor(ss, d);
  const float r = rsqrtf(ss * (1.0f / 256.0f) + 1e-6f);
  float v[4];
#pragma unroll
  for (int c = 0; c < 4; ++c) v[c] = x[c] * r * (1.0f + scale[l * 4 + c]);
  if (ROPE) {
    const float pos = (float)pos_ids[token];
    float o[4];
#pragma unroll
    for (int c = 0; c < 4; ++c) {
      const int j = (l & 31) * 4 + c;
      const float inv_ts = exp2f(-(float)j * 0.10381025296523007f);
      const float arg = pos * inv_ts;
      const float sj = sinf(arg), cj = cosf(arg);
      const float partner = __shfl_xor(v[c], 32);
      o[c] = (l < 32) ? (v[c] * cj - partner * sj) : (v[c] * cj + partner * sj);
    }
#pragma unroll
    for (int c = 0; c < 4; ++c) v[c] = o[c];
  }
  bf16 ob[4];
#pragma unroll
  for (int c = 0; c < 4; ++c) ob[c] = __float2bfloat16(v[c] * mul);
  const size_t doff = ((size_t)((b * nheads + n) * dst_S + dst_t0 + t)) * 256 + l * 4;
  *reinterpret_cast<uint64_t*>(dst + doff) = *reinterpret_cast<uint64_t*>(ob);
}

// ---------------- fused attention (no staging, s-split, head-paired, barrier-free loop) ----------------
// grid 256 blocks (XCD-swizzled: 16 qt x 16 b*kvh), 512 threads / 8 waves.
// Wave w: q-subtile ws=w&3 (16 rows of the 64-row qt tile), s-half h=w>>2.
// Each wave computes BOTH GQA heads (one K/V read feeds 2 MFMAs).
// Groups h=0/1 take even/odd s-tiles; partial O and rowsum merged once at the end
// (softcap bounds logits to +-50 -> plain sum-softmax, partials add trivially).
// K/V read directly from global (L2-resident per XCD via swizzle) -> NO per-tile barriers.
__launch_bounds__(512, 2)
__global__ void attn_kernel(const bf16* __restrict__ qb, const bf16* __restrict__ kb,
                            const bf16* __restrict__ vt, bf16* __restrict__ attn_out) {
  __shared__ __align__(16) char smem[73728];
  bf16* pbuf = (bf16*)smem;              // [8 waves][2 heads][16*72] bf16 = 36864 B (loop phase)
  float* comb = (float*)smem;            // [4 ws][64 idx][64 lane] f32 = 65536 B (combine phase)
  float* rsb = (float*)(smem + 65536);   // [4 ws][2 g][4 j][64 lane] f32 = 8192 B

  const int lin = blockIdx.x + 16 * blockIdx.y;
  const int kvc = (lin & 7) | (((lin >> 7) & 1) << 3);  // XCD-coherent: lin%8 fixed per (b,kvh)
  const int qt = (lin >> 3) & 15;
  const int b = kvc >> 3, kvh = kvc & 7;
  const int tid = threadIdx.x, w = tid >> 6, l = tid & 63;
  const int ws = w & 3;   // q-subtile
  const int h = w >> 2;   // s-half group
  const int l15 = l & 15, lhi = l >> 4;

  const bf16* kbase = kb + (size_t)(b * 8 + kvh) * 2048 * 256;
  const bf16* vbase = vt + (size_t)(b * 8 + kvh) * 256 * 2048;

  // Q fragments for both heads (register-resident)
  bv8 qf[2][8];
#pragma unroll
  for (int g = 0; g < 2; ++g) {
    const bf16* qp = qb +
        ((size_t)(b * 16 + kvh * 2 + g) * 1024 + qt * 64 + ws * 16 + l15) * 256 + lhi * 8;
#pragma unroll
    for (int f = 0; f < 8; ++f) qf[g][f] = *reinterpret_cast<const bv8*>(qp + f * 32);
  }

  f32x4 oacc[2][16] = {};
  float rs[2][4] = {};
  bf16* pb0 = pbuf + (w * 2 + 0) * 1152;
  bf16* pb1 = pbuf + (w * 2 + 1) * 1152;

  const int nt = qt + 17;  // qt+1 self tiles + 16 cross tiles
  for (int it = h; it < nt; it += 2) {
    const int s0 = (it <= qt) ? it * 64 : 1024 + (it - qt - 1) * 64;
    // ---- QK^T: one K-frag global read feeds both heads ----
    f32x4 lacc[2][4] = {};
#pragma unroll
    for (int sub = 0; sub < 4; ++sub) {
      const bf16* kp = kbase + (size_t)(s0 + sub * 16 + l15) * 256 + lhi * 8;
#pragma unroll
      for (int f = 0; f < 8; ++f) {
        bv8 kf = *reinterpret_cast<const bv8*>(kp + f * 32);
        lacc[0][sub] = mfma16(qf[0][f], kf, lacc[0][sub]);
        lacc[1][sub] = mfma16(qf[1][f], kf, lacc[1][sub]);
      }
    }
    // ---- softcap + mask + exp -> wave-private P tiles ----
    const bool diag = (it == qt);
#pragma unroll
    for (int g = 0; g < 2; ++g) {
      bf16* pb = g ? pb1 : pb0;
#pragma unroll
      for (int sub = 0; sub < 4; ++sub)
#pragma unroll
        for (int j = 0; j < 4; ++j) {
          const float raw = lacc[g][sub][j];
          const float e2 = __expf(raw * 0.04f);  // e^(2*raw/50)
          // exp(50*tanh(raw/50)) = exp(50 - 100/(e2+1))
          const bool ok = !diag || (sub * 16 + l15 <= ws * 16 + lhi * 4 + j);
          const float p = ok ? __expf(50.f - __fdividef(100.f, e2 + 1.f)) : 0.f;
          rs[g][j] += p;
          pb[(lhi * 4 + j) * 72 + sub * 16 + l15] = __float2bfloat16(p);
        }
    }
    // wave-internal ordering of P write -> P read (pbuf is wave-private)
    asm volatile("s_waitcnt lgkmcnt(0)" ::: "memory");
    __builtin_amdgcn_sched_barrier(0);
    // ---- P @ V: one V-frag global read feeds both heads ----
#pragma unroll
    for (int ks = 0; ks < 2; ++ks) {
      bv8 pa0 = *reinterpret_cast<const bv8*>(pb0 + l15 * 72 + ks * 32 + lhi * 8);
      bv8 pa1 = *reinterpret_cast<const bv8*>(pb1 + l15 * 72 + ks * 32 + lhi * 8);
      const bf16* vp = vbase + s0 + ks * 32 + lhi * 8;
#pragma unroll
      for (int ht = 0; ht < 16; ++ht) {
        bv8 vf = *reinterpret_cast<const bv8*>(vp + (size_t)(ht * 16 + l15) * 2048);
        oacc[0][ht] = mfma16(pa0, vf, oacc[0][ht]);
        oacc[1][ht] = mfma16(pa1, vf, oacc[1][ht]);
      }
    }
  }

  // ---- end-of-kernel combine: group B (h=1) partials merged into group A, 2 head passes ----
  __syncthreads();  // all waves done with pbuf; comb/rsb may now alias it
  if (h == 1) {
    float* cb = comb + ws * 4096;
#pragma unroll
    for (int ht = 0; ht < 16; ++ht)
#pragma unroll
      for (int j = 0; j < 4; ++j)
        cb[(ht * 4 + j) * 64 + l] = oacc[0][ht][j];
#pragma unroll
    for (int g = 0; g < 2; ++g)
#pragma unroll
      for (int j = 0; j < 4; ++j)
        rsb[((ws * 2 + g) * 4 + j) * 64 + l] = rs[g][j];
  }
  __syncthreads();
  float invr[2][4];
  if (h == 0) {
    float* cb = comb + ws * 4096;
#pragma unroll
    for (int ht = 0; ht < 16; ++ht)
#pragma unroll
      for (int j = 0; j < 4; ++j)
        oacc[0][ht][j] += cb[(ht * 4 + j) * 64 + l];
#pragma unroll
    for (int g = 0; g < 2; ++g)
#pragma unroll
      for (int j = 0; j < 4; ++j) {
        float s = rs[g][j] + rsb[((ws * 2 + g) * 4 + j) * 64 + l];
        s += __shfl_xor(s, 1);
        s += __shfl_xor(s, 2);
        s += __shfl_xor(s, 4);
        s += __shfl_xor(s, 8);
        invr[g][j] = 1.0f / s;
      }
    bf16* op = attn_out + ((size_t)(b * 1024 + qt * 64 + ws * 16 + lhi * 4) * 4096) +
               (kvh * 2 + 0) * 256 + l15;
#pragma unroll
    for (int ht = 0; ht < 16; ++ht)
#pragma unroll
      for (int j = 0; j < 4; ++j)
        op[(size_t)j * 4096 + ht * 16] = __float2bfloat16(oacc[0][ht][j] * invr[0][j]);
  }
  __syncthreads();
  if (h == 1) {
    float* cb = comb + ws * 4096;
#pragma unroll
    for (int ht = 0; ht < 16; ++ht)
#pragma unroll
      for (int j = 0; j < 4; ++j)
        cb[(ht * 4 + j) * 64 + l] = oacc[1][ht][j];
  }
  __syncthreads();
  if (h == 0) {
    float* cb = comb + ws * 4096;
#pragma unroll
    for (int ht = 0; ht < 16; ++ht)
#pragma unroll
      for (int j = 0; j < 4; ++j)
        oacc[1][ht][j] += cb[(ht * 4 + j) * 64 + l];
    bf16* op = attn_out + ((size_t)(b * 1024 + qt * 64 + ws * 16 + lhi * 4) * 4096) +
               (kvh * 2 + 1) * 256 + l15;
#pragma unroll
    for (int ht = 0; ht < 16; ++ht)
#pragma unroll
      for (int j = 0; j < 4; ++j)
        op[(size_t)j * 4096 + ht * 16] = __float2bfloat16(oacc[1][ht][j] * invr[1][j]);
  }
}

// ---------------- host launcher ----------------
extern "C" void kernel_launch(void* const* d_in, const int* in_sizes, int n_in,
                              void* d_out, int out_size, void* d_ws, size_t ws_size,
                              hipStream_t stream) {
  (void)in_sizes; (void)n_in; (void)out_size; (void)ws_size;
  const float* hidden = (const float*)d_in[0];
  const float* enc    = (const float*)d_in[1];
  const int*   pos    = (const int*)d_in[2];
  // d_in[3] = merged_attention_mask: deterministic (causal|ones) -> computed analytically
  const float* q_w = (const float*)d_in[4];
  const float* k_w = (const float*)d_in[5];
  const float* v_w = (const float*)d_in[6];
  const float* o_w = (const float*)d_in[7];
  const float* q_s = (const float*)d_in[8];
  const float* k_s = (const float*)d_in[9];
  float* out = (float*)d_out;

  // workspace layout (117,440,512 bytes), write-before-read aliasing (single stream):
  char* base = (char*)d_ws;
  bf16* hid_b  = (bf16*)(base + 0);          // [2048][2048]
  bf16* enc_b  = (bf16*)(base + 8388608);    // [2048][2048]
  bf16* qb     = (bf16*)(base + 0);          // [2][16][1024][256]
  bf16* wqkvt  = (bf16*)(base + 16777216);   // [8192][2048] = qwt|kwt|vwt
  bf16* kbuf   = (bf16*)(base + 16777216);   // [2][8][2048][256]
  bf16* vtb    = (bf16*)(base + 33554432);   // [2][8][256][2048]
  bf16* owt    = (bf16*)(base + 50331648);   // [2048][4096]
  bf16* cself  = (bf16*)(base + 67108864);   // [2048][8192] = q|k_self|v_self
  bf16* attn_b = (bf16*)(base + 67108864);   // [2048][4096]
  bf16* ccross = (bf16*)(base + 100663296);  // [2048][4096] = k_cross|v_cross

  dim3 tb32(32, 8);
  cast_f32_bf16<<<4096, 256, 0, stream>>>(hidden, hid_b, 1048576);
  cast_f32_bf16<<<4096, 256, 0, stream>>>(enc, enc_b, 1048576);
  transpose_cast<<<dim3(8, 64, 16), tb32, 0, stream>>>(q_w, wqkvt, 2048, 256);
  transpose_cast<<<dim3(8, 64, 8),  tb32, 0, stream>>>(k_w, wqkvt + 8388608, 2048, 256);
  transpose_cast<<<dim3(8, 64, 8),  tb32, 0, stream>>>(v_w, wqkvt + 12582912, 2048, 256);
  transpose_cast<<<dim3(64, 128, 1), tb32, 0, stream>>>(o_w, owt, 4096, 2048);
  gemm_bt<bf16><<<dim3(64, 16), 256, 0, stream>>>(hid_b, wqkvt, cself, 8192, 2048);
  gemm_bt<bf16><<<dim3(32, 16), 256, 0, stream>>>(enc_b, wqkvt + 8388608, ccross, 4096, 2048);
  norm_finalize<true><<<8192, 256, 0, stream>>>(cself, 8192, 0, q_s, pos, qb, 16, 1024, 0, 0.0625f);
  norm_finalize<true><<<4096, 256, 0, stream>>>(cself, 8192, 4096, k_s, pos, kbuf, 8, 2048, 0, 1.0f);
  norm_finalize<false><<<4096, 256, 0, stream>>>(ccross, 4096, 0, k_s, nullptr, kbuf, 8, 2048, 1024, 1.0f);
  transpose_v<<<dim3(8, 32, 16), tb32, 0, stream>>>(cself + 6144, 8192, vtb, 0);
  transpose_v<<<dim3(8, 32, 16), tb32, 0, stream>>>(ccross + 2048, 4096, vtb, 1024);
  attn_kernel<<<dim3(16, 16), 512, 0, stream>>>(qb, kbuf, vtb, attn_b);
  gemm_bt<float><<<dim3(16, 16), 256, 0, stream>>>(attn_b, owt, out, 2048, 4096);
}

// Round 6
// 451.749 us; speedup vs baseline: 1.4395x; 1.4395x over previous
//
#include <hip/hip_runtime.h>
#include <hip/hip_bf16.h>
#include <stdint.h>

typedef __hip_bfloat16 bf16;
typedef __attribute__((ext_vector_type(8))) short bv8;    // 8 x bf16 (mfma A/B frag)
typedef __attribute__((ext_vector_type(4))) float f32x4;  // mfma C/D frag

// Problem constants: B=2, T=1024, S_ENC=1024, D=2048, NQ=16, NKV=8, H=256, SKV=2048

__device__ __forceinline__ f32x4 mfma16(bv8 a, bv8 b, f32x4 c) {
  return __builtin_amdgcn_mfma_f32_16x16x32_bf16(a, b, c, 0, 0, 0);
}

__device__ __forceinline__ void gload16(const void* g, void* lds) {
  __builtin_amdgcn_global_load_lds((const __attribute__((address_space(1))) void*)g,
                                   (__attribute__((address_space(3))) void*)lds, 16, 0, 0);
}

__device__ __forceinline__ void storeC(float* p, float v) { *p = v; }
__device__ __forceinline__ void storeC(bf16* p, float v) { *p = __float2bfloat16(v); }

// ---------------- elementwise f32 -> bf16 ----------------
__global__ void cast_f32_bf16(const float* __restrict__ src, bf16* __restrict__ dst, int n4) {
  int i = blockIdx.x * blockDim.x + threadIdx.x;
  if (i >= n4) return;
  float4 v = reinterpret_cast<const float4*>(src)[i];
  bf16 t[4] = {__float2bfloat16(v.x), __float2bfloat16(v.y),
               __float2bfloat16(v.z), __float2bfloat16(v.w)};
  reinterpret_cast<uint64_t*>(dst)[i] = *reinterpret_cast<uint64_t*>(t);
}

// ------- batched transpose+cast: src f32 [z][R][C] -> dst bf16 [z][C][R] -------
__global__ void transpose_cast(const float* __restrict__ src, bf16* __restrict__ dst,
                               int R, int C) {
  __shared__ float tile[32][33];
  const int z = blockIdx.z;
  const float* s = src + (size_t)z * R * C;
  bf16* d = dst + (size_t)z * R * C;
  const int c0 = blockIdx.x * 32, r0 = blockIdx.y * 32;
  const int x = threadIdx.x, y = threadIdx.y;
#pragma unroll
  for (int i = 0; i < 32; i += 8)
    tile[y + i][x] = s[(size_t)(r0 + y + i) * C + c0 + x];
  __syncthreads();
#pragma unroll
  for (int i = 0; i < 32; i += 8)
    d[(size_t)(c0 + y + i) * R + r0 + x] = __float2bfloat16(tile[x][y + i]);
}

// ------- V transpose (bf16 in): per (b,kvh): [1024 t][256 h] -> vt [256 h][2048 s] -------
__global__ void transpose_v(const bf16* __restrict__ src, int src_ld,
                            bf16* __restrict__ dst, int t0) {
  __shared__ bf16 tile[32][33];
  const int z = blockIdx.z, b = z >> 3, kvh = z & 7;
  const bf16* s = src + (size_t)(b * 1024) * src_ld + kvh * 256;
  bf16* d = dst + (size_t)(z * 256) * 2048 + t0;
  const int h0 = blockIdx.x * 32, tt0 = blockIdx.y * 32;
  const int x = threadIdx.x, y = threadIdx.y;
#pragma unroll
  for (int i = 0; i < 32; i += 8)
    tile[y + i][x] = s[(size_t)(tt0 + y + i) * src_ld + h0 + x];
  __syncthreads();
#pragma unroll
  for (int i = 0; i < 32; i += 8)
    d[(size_t)(h0 + y + i) * 2048 + tt0 + x] = tile[x][y + i];
}

// ---------------- GEMM: C[M][N] = A[M][K] * Bt[N][K]^T  (m97-style 128x128, BK=32) ----------------
template <typename CT>
__launch_bounds__(256)
__global__ void gemm_bt(const bf16* __restrict__ A, const bf16* __restrict__ Bt,
                        CT* __restrict__ C, int N, int K) {
  __shared__ __align__(16) bf16 As[128 * 32];
  __shared__ __align__(16) bf16 Bs[128 * 32];
  const int tid = threadIdx.x;
  const int w = tid >> 6, l = tid & 63;
  const int wr = w >> 1, wc = w & 1;
  const int l15 = l & 15, lhi = l >> 4;
  const int m0 = blockIdx.y * 128, n0 = blockIdx.x * 128;
  const bf16* ag = A + (size_t)(m0 + (tid >> 2)) * K + (tid & 3) * 8;
  const bf16* bg = Bt + (size_t)(n0 + (tid >> 2)) * K + (tid & 3) * 8;
  bf16* asw = As + w * 512;
  bf16* bsw = Bs + w * 512;
  f32x4 acc[4][4] = {};
  for (int k0 = 0; k0 < K; k0 += 32) {
    gload16(ag + k0, asw);
    gload16(ag + (size_t)64 * K + k0, asw + 2048);
    gload16(bg + k0, bsw);
    gload16(bg + (size_t)64 * K + k0, bsw + 2048);
    asm volatile("s_waitcnt vmcnt(0)" ::: "memory");
    __syncthreads();
    bv8 af[4], bfv[4];
#pragma unroll
    for (int m = 0; m < 4; ++m)
      af[m] = *reinterpret_cast<const bv8*>(As + (wr * 64 + m * 16 + l15) * 32 + lhi * 8);
#pragma unroll
    for (int n = 0; n < 4; ++n)
      bfv[n] = *reinterpret_cast<const bv8*>(Bs + (wc * 64 + n * 16 + l15) * 32 + lhi * 8);
#pragma unroll
    for (int m = 0; m < 4; ++m)
#pragma unroll
      for (int n = 0; n < 4; ++n)
        acc[m][n] = mfma16(af[m], bfv[n], acc[m][n]);
    __syncthreads();
  }
  const int r0 = m0 + wr * 64 + lhi * 4;
  const int c0 = n0 + wc * 64 + l15;
#pragma unroll
  for (int m = 0; m < 4; ++m)
#pragma unroll
    for (int n = 0; n < 4; ++n) {
      f32x4 v = acc[m][n];
#pragma unroll
      for (int j = 0; j < 4; ++j)
        storeC(&C[(size_t)(r0 + m * 16 + j) * N + c0 + n * 16], v[j]);
    }
}

// ---------------- RMSNorm (+optional RoPE) + scale ----------------
template <bool ROPE>
__launch_bounds__(256)
__global__ void norm_finalize(const bf16* __restrict__ src, int src_ld, int src_col0,
                              const float* __restrict__ scale,
                              const int* __restrict__ pos_ids,
                              bf16* __restrict__ dst, int nheads, int dst_S, int dst_t0,
                              float mul) {
  const int gid = blockIdx.x * 4 + (threadIdx.x >> 6);
  const int l = threadIdx.x & 63;
  const int token = gid / nheads;
  const int n = gid - token * nheads;
  const int b = token >> 10;
  const int t = token & 1023;
  const size_t soff = (size_t)token * src_ld + src_col0 + n * 256 + l * 4;
  bf16 xb[4];
  *reinterpret_cast<uint64_t*>(xb) = *reinterpret_cast<const uint64_t*>(src + soff);
  float x[4];
#pragma unroll
  for (int c = 0; c < 4; ++c) x[c] = __bfloat162float(xb[c]);
  float ss = x[0] * x[0] + x[1] * x[1] + x[2] * x[2] + x[3] * x[3];
#pragma unroll
  for (int d = 1; d < 64; d <<= 1) ss += __shfl_xor(ss, d);
  const float r = rsqrtf(ss * (1.0f / 256.0f) + 1e-6f);
  float v[4];
#pragma unroll
  for (int c = 0; c < 4; ++c) v[c] = x[c] * r * (1.0f + scale[l * 4 + c]);
  if (ROPE) {
    const float pos = (float)pos_ids[token];
    float o[4];
#pragma unroll
    for (int c = 0; c < 4; ++c) {
      const int j = (l & 31) * 4 + c;
      const float inv_ts = exp2f(-(float)j * 0.10381025296523007f);
      const float arg = pos * inv_ts;
      const float sj = sinf(arg), cj = cosf(arg);
      const float partner = __shfl_xor(v[c], 32);
      o[c] = (l < 32) ? (v[c] * cj - partner * sj) : (v[c] * cj + partner * sj);
    }
#pragma unroll
    for (int c = 0; c < 4; ++c) v[c] = o[c];
  }
  bf16 ob[4];
#pragma unroll
  for (int c = 0; c < 4; ++c) ob[c] = __float2bfloat16(v[c] * mul);
  const size_t doff = ((size_t)((b * nheads + n) * dst_S + dst_t0 + t)) * 256 + l * 4;
  *reinterpret_cast<uint64_t*>(dst + doff) = *reinterpret_cast<uint64_t*>(ob);
}

// ---------------- fused attention (round-3 structure + XCD swizzle + setprio) ----------------
// 256 blocks (XCD-swizzled: all 16 qt-blocks of one (b,kvh) on one XCD), 512 thr / 8 waves.
// waves 0-3: head g=0, q rows (w&3)*16; waves 4-7: head g=1, same rows.
// K tile [64 s][256 h] + V^T tile [256 h][64 s] staged in LDS via global_load_lds,
// XOR-swizzled (byte ^= (row&7)<<4) with pre-swizzled global source (linear LDS dest).
// Softcap bounds logits to +-50 -> plain sum-softmax, no online max.
__launch_bounds__(512, 2)
__global__ void attn_kernel(const bf16* __restrict__ qb, const bf16* __restrict__ kb,
                            const bf16* __restrict__ vt, bf16* __restrict__ attn_out) {
  __shared__ __align__(16) bf16 Ks[2][64 * 256];   // 32KB each
  __shared__ __align__(16) bf16 Vs[2][256 * 64];   // 32KB each
  __shared__ __align__(16) bf16 pbuf[8][16 * 72];  // rows padded to 144B
  // XCD-coherent swizzle: lin%8 (and bit7) fixed per (b,kvh) -> K/V L2-resident per XCD
  const int lin = blockIdx.x + 16 * blockIdx.y;
  const int kvc = (lin & 7) | (((lin >> 7) & 1) << 3);
  const int qt  = (lin >> 3) & 15;
  const int b = kvc >> 3, kvh = kvc & 7;
  const int tid = threadIdx.x, w = tid >> 6, l = tid & 63;
  const int wq = w & 3, g = w >> 2;
  const int n = kvh * 2 + g;
  const int l15 = l & 15, lhi = l >> 4;
  const int xr = (l15 & 7) << 4;  // frag-read byte swizzle

  const bf16* kbase = kb + (size_t)(b * 8 + kvh) * 2048 * 256;
  const bf16* vbase = vt + (size_t)(b * 8 + kvh) * 256 * 2048;

  // per-lane staging sources (tile-invariant part), pre-swizzled columns
  const bf16* ksrc[4];
  const bf16* vsrc[4];
#pragma unroll
  for (int i = 0; i < 4; ++i) {
    const int r0 = (w * 4 + i) * 2 + (l >> 5);            // K row 0..63
    const int cbs = ((l & 31) * 16) ^ ((r0 & 7) << 4);    // byte in 512B row
    ksrc[i] = kbase + r0 * 256 + (cbs >> 1);
    const int h0 = (w * 4 + i) * 8 + (l >> 3);            // V row (h) 0..255
    const int cbv = ((l & 7) * 16) ^ ((h0 & 7) << 4);     // byte in 128B row
    vsrc[i] = vbase + (size_t)h0 * 2048 + (cbv >> 1);
  }

  // Q fragments (register-resident for whole kernel)
  const bf16* qptr = qb + ((size_t)(b * 16 + n) * 1024 + qt * 64 + wq * 16 + l15) * 256 + lhi * 8;
  bv8 qf[8];
#pragma unroll
  for (int f = 0; f < 8; ++f) qf[f] = *reinterpret_cast<const bv8*>(qptr + f * 32);

  f32x4 oacc[16] = {};
  float rs[4] = {0.f, 0.f, 0.f, 0.f};

  const int nt = qt + 17;  // qt+1 self tiles + 16 cross tiles

  // prologue: stage tile 0
#pragma unroll
  for (int i = 0; i < 4; ++i) gload16(ksrc[i], &Ks[0][(w * 4 + i) * 512]);
#pragma unroll
  for (int i = 0; i < 4; ++i) gload16(vsrc[i], &Vs[0][(w * 4 + i) * 512]);
  asm volatile("s_waitcnt vmcnt(0)" ::: "memory");
  __syncthreads();

  for (int it = 0; it < nt; ++it) {
    const int cur = it & 1;
    if (it + 1 < nt) {  // stage next tile into the other buffer (overlaps compute)
      const int itn = it + 1;
      const int s1 = (itn <= qt) ? itn * 64 : 1024 + (itn - qt - 1) * 64;
#pragma unroll
      for (int i = 0; i < 4; ++i)
        gload16(ksrc[i] + (size_t)s1 * 256, &Ks[cur ^ 1][(w * 4 + i) * 512]);
#pragma unroll
      for (int i = 0; i < 4; ++i)
        gload16(vsrc[i] + s1, &Vs[cur ^ 1][(w * 4 + i) * 512]);
    }
    // ---- QK^T from LDS ----
    f32x4 lacc[4] = {};
    __builtin_amdgcn_s_setprio(1);
#pragma unroll
    for (int sub = 0; sub < 4; ++sub) {
      const int rbase = (sub * 16 + l15) * 256;
#pragma unroll
      for (int f = 0; f < 8; ++f) {
        const int off = rbase + (((f * 64 + lhi * 16) ^ xr) >> 1);
        bv8 kf = *reinterpret_cast<const bv8*>(&Ks[cur][off]);
        lacc[sub] = mfma16(qf[f], kf, lacc[sub]);
      }
    }
    __builtin_amdgcn_s_setprio(0);
    // ---- softcap + mask + exp -> wave-private P tile ----
    const bool diag = (it == qt);  // only diagonal tile needs the causal test
#pragma unroll
    for (int sub = 0; sub < 4; ++sub) {
#pragma unroll
      for (int j = 0; j < 4; ++j) {
        const float raw = lacc[sub][j];
        const float e2 = __expf(raw * 0.04f);  // e^(2*raw/50)
        // exp(50*tanh(raw/50)) = exp(50 - 100/(e2+1))
        const bool ok = !diag || (sub * 16 + l15 <= wq * 16 + lhi * 4 + j);
        const float p = ok ? __expf(50.f - __fdividef(100.f, e2 + 1.f)) : 0.f;
        rs[j] += p;
        pbuf[w][(lhi * 4 + j) * 72 + sub * 16 + l15] = __float2bfloat16(p);
      }
    }
    __syncthreads();  // P visible (canonical barrier)
    // ---- P @ V from LDS ----
    __builtin_amdgcn_s_setprio(1);
#pragma unroll
    for (int ks = 0; ks < 2; ++ks) {
      bv8 pa = *reinterpret_cast<const bv8*>(&pbuf[w][l15 * 72 + ks * 32 + lhi * 8]);
#pragma unroll
      for (int ht = 0; ht < 16; ++ht) {
        const int off = (ht * 16 + l15) * 64 + (((ks * 64 + lhi * 16) ^ xr) >> 1);
        bv8 vf = *reinterpret_cast<const bv8*>(&Vs[cur][off]);
        oacc[ht] = mfma16(pa, vf, oacc[ht]);
      }
    }
    __builtin_amdgcn_s_setprio(0);
    asm volatile("s_waitcnt vmcnt(0)" ::: "memory");  // staged tile landed
    __syncthreads();  // reads of cur done; next iter may overwrite
  }
  // normalize and store
  float invr[4];
#pragma unroll
  for (int j = 0; j < 4; ++j) {
    float s = rs[j];
    s += __shfl_xor(s, 1);
    s += __shfl_xor(s, 2);
    s += __shfl_xor(s, 4);
    s += __shfl_xor(s, 8);
    invr[j] = 1.0f / s;
  }
  bf16* op = attn_out + ((size_t)(b * 1024 + qt * 64 + wq * 16 + lhi * 4) * 4096) + n * 256 + l15;
#pragma unroll
  for (int ht = 0; ht < 16; ++ht)
#pragma unroll
    for (int j = 0; j < 4; ++j)
      op[(size_t)j * 4096 + ht * 16] = __float2bfloat16(oacc[ht][j] * invr[j]);
}

// ---------------- host launcher ----------------
extern "C" void kernel_launch(void* const* d_in, const int* in_sizes, int n_in,
                              void* d_out, int out_size, void* d_ws, size_t ws_size,
                              hipStream_t stream) {
  (void)in_sizes; (void)n_in; (void)out_size; (void)ws_size;
  const float* hidden = (const float*)d_in[0];
  const float* enc    = (const float*)d_in[1];
  const int*   pos    = (const int*)d_in[2];
  // d_in[3] = merged_attention_mask: deterministic (causal|ones) -> computed analytically
  const float* q_w = (const float*)d_in[4];
  const float* k_w = (const float*)d_in[5];
  const float* v_w = (const float*)d_in[6];
  const float* o_w = (const float*)d_in[7];
  const float* q_s = (const float*)d_in[8];
  const float* k_s = (const float*)d_in[9];
  float* out = (float*)d_out;

  // workspace layout (117,440,512 bytes), write-before-read aliasing (single stream):
  char* base = (char*)d_ws;
  bf16* hid_b  = (bf16*)(base + 0);          // [2048][2048]
  bf16* enc_b  = (bf16*)(base + 8388608);    // [2048][2048]
  bf16* qb     = (bf16*)(base + 0);          // [2][16][1024][256]
  bf16* wqkvt  = (bf16*)(base + 16777216);   // [8192][2048] = qwt|kwt|vwt
  bf16* kbuf   = (bf16*)(base + 16777216);   // [2][8][2048][256]
  bf16* vtb    = (bf16*)(base + 33554432);   // [2][8][256][2048]
  bf16* owt    = (bf16*)(base + 50331648);   // [2048][4096]
  bf16* cself  = (bf16*)(base + 67108864);   // [2048][8192] = q|k_self|v_self
  bf16* attn_b = (bf16*)(base + 67108864);   // [2048][4096]
  bf16* ccross = (bf16*)(base + 100663296);  // [2048][4096] = k_cross|v_cross

  dim3 tb32(32, 8);
  cast_f32_bf16<<<4096, 256, 0, stream>>>(hidden, hid_b, 1048576);
  cast_f32_bf16<<<4096, 256, 0, stream>>>(enc, enc_b, 1048576);
  transpose_cast<<<dim3(8, 64, 16), tb32, 0, stream>>>(q_w, wqkvt, 2048, 256);
  transpose_cast<<<dim3(8, 64, 8),  tb32, 0, stream>>>(k_w, wqkvt + 8388608, 2048, 256);
  transpose_cast<<<dim3(8, 64, 8),  tb32, 0, stream>>>(v_w, wqkvt + 12582912, 2048, 256);
  transpose_cast<<<dim3(64, 128, 1), tb32, 0, stream>>>(o_w, owt, 4096, 2048);
  gemm_bt<bf16><<<dim3(64, 16), 256, 0, stream>>>(hid_b, wqkvt, cself, 8192, 2048);
  gemm_bt<bf16><<<dim3(32, 16), 256, 0, stream>>>(enc_b, wqkvt + 8388608, ccross, 4096, 2048);
  norm_finalize<true><<<8192, 256, 0, stream>>>(cself, 8192, 0, q_s, pos, qb, 16, 1024, 0, 0.0625f);
  norm_finalize<true><<<4096, 256, 0, stream>>>(cself, 8192, 4096, k_s, pos, kbuf, 8, 2048, 0, 1.0f);
  norm_finalize<false><<<4096, 256, 0, stream>>>(ccross, 4096, 0, k_s, nullptr, kbuf, 8, 2048, 1024, 1.0f);
  transpose_v<<<dim3(8, 32, 16), tb32, 0, stream>>>(cself + 6144, 8192, vtb, 0);
  transpose_v<<<dim3(8, 32, 16), tb32, 0, stream>>>(ccross + 2048, 4096, vtb, 1024);
  attn_kernel<<<dim3(16, 16), 512, 0, stream>>>(qb, kbuf, vtb, attn_b);
  gemm_bt<float><<<dim3(16, 16), 256, 0, stream>>>(attn_b, owt, out, 2048, 4096);
}

// Round 7
// 376.374 us; speedup vs baseline: 1.7278x; 1.2003x over previous
//
#include <hip/hip_runtime.h>
#include <hip/hip_bf16.h>
#include <stdint.h>

typedef __hip_bfloat16 bf16;
typedef __attribute__((ext_vector_type(8))) short bv8;    // 8 x bf16 (mfma A/B frag)
typedef __attribute__((ext_vector_type(4))) float f32x4;  // mfma C/D frag

// Problem constants: B=2, T=1024, S_ENC=1024, D=2048, NQ=16, NKV=8, H=256, SKV=2048

__device__ __forceinline__ f32x4 mfma16(bv8 a, bv8 b, f32x4 c) {
  return __builtin_amdgcn_mfma_f32_16x16x32_bf16(a, b, c, 0, 0, 0);
}

__device__ __forceinline__ void gload16(const void* g, void* lds) {
  __builtin_amdgcn_global_load_lds((const __attribute__((address_space(1))) void*)g,
                                   (__attribute__((address_space(3))) void*)lds, 16, 0, 0);
}

__device__ __forceinline__ void storeC(float* p, float v) { *p = v; }
__device__ __forceinline__ void storeC(bf16* p, float v) { *p = __float2bfloat16(v); }

// ---------------- merged elementwise f32 -> bf16 (both activations, 1 launch) ----------------
__global__ void cast2_f32_bf16(const float* __restrict__ a, const float* __restrict__ b,
                               bf16* __restrict__ da, bf16* __restrict__ db, int n4each) {
  int i = blockIdx.x * blockDim.x + threadIdx.x;
  const float* s;
  bf16* d;
  if (i < n4each) { s = a; d = da; }
  else            { s = b; d = db; i -= n4each; }
  float4 v = reinterpret_cast<const float4*>(s)[i];
  bf16 t[4] = {__float2bfloat16(v.x), __float2bfloat16(v.y),
               __float2bfloat16(v.z), __float2bfloat16(v.w)};
  reinterpret_cast<uint64_t*>(d)[i] = *reinterpret_cast<uint64_t*>(t);
}

// ------- merged QKV weight transpose+cast: 32 head-slices [2048][256] -> [256][2048] -------
__global__ void transpose_cast_qkv(const float* __restrict__ q_w, const float* __restrict__ k_w,
                                   const float* __restrict__ v_w, bf16* __restrict__ dst) {
  __shared__ float tile[32][33];
  const int z = blockIdx.z;
  const float* s = (z < 16) ? q_w + (size_t)z * 524288
                 : (z < 24) ? k_w + (size_t)(z - 16) * 524288
                            : v_w + (size_t)(z - 24) * 524288;
  bf16* d = dst + (size_t)z * 524288;
  const int R = 2048, C = 256;
  const int c0 = blockIdx.x * 32, r0 = blockIdx.y * 32;
  const int x = threadIdx.x, y = threadIdx.y;
#pragma unroll
  for (int i = 0; i < 32; i += 8)
    tile[y + i][x] = s[(size_t)(r0 + y + i) * C + c0 + x];
  __syncthreads();
#pragma unroll
  for (int i = 0; i < 32; i += 8)
    d[(size_t)(c0 + y + i) * R + r0 + x] = __float2bfloat16(tile[x][y + i]);
}

// ------- O-weight transpose+cast: [4096][2048] -> [2048][4096] -------
__global__ void transpose_cast(const float* __restrict__ src, bf16* __restrict__ dst,
                               int R, int C) {
  __shared__ float tile[32][33];
  const float* s = src;
  bf16* d = dst;
  const int c0 = blockIdx.x * 32, r0 = blockIdx.y * 32;
  const int x = threadIdx.x, y = threadIdx.y;
#pragma unroll
  for (int i = 0; i < 32; i += 8)
    tile[y + i][x] = s[(size_t)(r0 + y + i) * C + c0 + x];
  __syncthreads();
#pragma unroll
  for (int i = 0; i < 32; i += 8)
    d[(size_t)(c0 + y + i) * R + r0 + x] = __float2bfloat16(tile[x][y + i]);
}

// ------- merged V transpose: z<16 self (ld 8192, t0=0), else cross (ld 4096, t0=1024) -------
__global__ void transpose_v2(const bf16* __restrict__ vself, const bf16* __restrict__ vcross,
                             bf16* __restrict__ dst) {
  __shared__ bf16 tile[32][33];
  const int z = blockIdx.z;
  const int zz = z & 15, b = zz >> 3, kvh = zz & 7;
  const bool cross = z >= 16;
  const bf16* srcb = cross ? vcross : vself;
  const int src_ld = cross ? 4096 : 8192;
  const int t0 = cross ? 1024 : 0;
  const bf16* s = srcb + (size_t)(b * 1024) * src_ld + kvh * 256;
  bf16* d = dst + (size_t)(zz * 256) * 2048 + t0;
  const int h0 = blockIdx.x * 32, tt0 = blockIdx.y * 32;
  const int x = threadIdx.x, y = threadIdx.y;
#pragma unroll
  for (int i = 0; i < 32; i += 8)
    tile[y + i][x] = s[(size_t)(tt0 + y + i) * src_ld + h0 + x];
  __syncthreads();
#pragma unroll
  for (int i = 0; i < 32; i += 8)
    d[(size_t)(h0 + y + i) * 2048 + tt0 + x] = tile[x][y + i];
}

// ---------------- GEMM body: C[M][N] = A[M][K] * Bt[N][K]^T (m97 128x128, BK=32) ----------------
template <typename CT>
__device__ __forceinline__ void gemm_body(const bf16* __restrict__ A, const bf16* __restrict__ Bt,
                                          CT* __restrict__ C, int N, int K,
                                          int m0, int n0, int kbase, int ksteps) {
  __shared__ __align__(16) bf16 As[128 * 32];
  __shared__ __align__(16) bf16 Bs[128 * 32];
  const int tid = threadIdx.x;
  const int w = tid >> 6, l = tid & 63;
  const int wr = w >> 1, wc = w & 1;
  const int l15 = l & 15, lhi = l >> 4;
  const bf16* ag = A + (size_t)(m0 + (tid >> 2)) * K + kbase + (tid & 3) * 8;
  const bf16* bg = Bt + (size_t)(n0 + (tid >> 2)) * K + kbase + (tid & 3) * 8;
  bf16* asw = As + w * 512;
  bf16* bsw = Bs + w * 512;
  f32x4 acc[4][4] = {};
  for (int k0 = 0; k0 < ksteps; k0 += 32) {
    gload16(ag + k0, asw);
    gload16(ag + (size_t)64 * K + k0, asw + 2048);
    gload16(bg + k0, bsw);
    gload16(bg + (size_t)64 * K + k0, bsw + 2048);
    asm volatile("s_waitcnt vmcnt(0)" ::: "memory");
    __syncthreads();
    bv8 af[4], bfv[4];
#pragma unroll
    for (int m = 0; m < 4; ++m)
      af[m] = *reinterpret_cast<const bv8*>(As + (wr * 64 + m * 16 + l15) * 32 + lhi * 8);
#pragma unroll
    for (int n = 0; n < 4; ++n)
      bfv[n] = *reinterpret_cast<const bv8*>(Bs + (wc * 64 + n * 16 + l15) * 32 + lhi * 8);
#pragma unroll
    for (int m = 0; m < 4; ++m)
#pragma unroll
      for (int n = 0; n < 4; ++n)
        acc[m][n] = mfma16(af[m], bfv[n], acc[m][n]);
    __syncthreads();
  }
  const int r0 = m0 + wr * 64 + lhi * 4;
  const int c0 = n0 + wc * 64 + l15;
#pragma unroll
  for (int m = 0; m < 4; ++m)
#pragma unroll
    for (int n = 0; n < 4; ++n) {
      f32x4 v = acc[m][n];
#pragma unroll
      for (int j = 0; j < 4; ++j)
        storeC(&C[(size_t)(r0 + m * 16 + j) * N + c0 + n * 16], v[j]);
    }
}

// merged self+cross projection GEMM: bx<64 -> self (N=8192), else cross (N=4096)
__launch_bounds__(256)
__global__ void gemm_proj(const bf16* __restrict__ hid, const bf16* __restrict__ enc,
                          const bf16* __restrict__ wqkvt, bf16* __restrict__ cself,
                          bf16* __restrict__ ccross) {
  const int bx = blockIdx.x;
  const bool cross = bx >= 64;
  const bf16* A = cross ? enc : hid;
  const bf16* Bt = cross ? wqkvt + 8388608 : wqkvt;
  bf16* C = cross ? ccross : cself;
  const int N = cross ? 4096 : 8192;
  const int n0 = (cross ? bx - 64 : bx) * 128;
  gemm_body<bf16>(A, Bt, C, N, 2048, blockIdx.y * 128, n0, 0, 2048);
}

// O-projection with split-K=2: z=0 -> out, z=1 -> partial p1 (both f32 [2048][2048])
__launch_bounds__(256)
__global__ void gemm_osplit(const bf16* __restrict__ A, const bf16* __restrict__ Bt,
                            float* __restrict__ out, float* __restrict__ p1) {
  float* C = blockIdx.z ? p1 : out;
  gemm_body<float>(A, Bt, C, 2048, 4096, blockIdx.y * 128, blockIdx.x * 128,
                   blockIdx.z * 2048, 2048);
}

// combine: out += p1 (float4)
__global__ void add_inplace(float* __restrict__ out, const float* __restrict__ p1, int n4) {
  int i = blockIdx.x * blockDim.x + threadIdx.x;
  if (i >= n4) return;
  float4 a = reinterpret_cast<float4*>(out)[i];
  float4 b = reinterpret_cast<const float4*>(p1)[i];
  a.x += b.x; a.y += b.y; a.z += b.z; a.w += b.w;
  reinterpret_cast<float4*>(out)[i] = a;
}

// ---------------- RMSNorm (+optional RoPE) + scale ----------------
template <bool ROPE>
__launch_bounds__(256)
__global__ void norm_finalize(const bf16* __restrict__ src, int src_ld, int src_col0,
                              const float* __restrict__ scale,
                              const int* __restrict__ pos_ids,
                              bf16* __restrict__ dst, int nheads, int dst_S, int dst_t0,
                              float mul) {
  const int gid = blockIdx.x * 4 + (threadIdx.x >> 6);
  const int l = threadIdx.x & 63;
  const int token = gid / nheads;
  const int n = gid - token * nheads;
  const int b = token >> 10;
  const int t = token & 1023;
  const size_t soff = (size_t)token * src_ld + src_col0 + n * 256 + l * 4;
  bf16 xb[4];
  *reinterpret_cast<uint64_t*>(xb) = *reinterpret_cast<const uint64_t*>(src + soff);
  float x[4];
#pragma unroll
  for (int c = 0; c < 4; ++c) x[c] = __bfloat162float(xb[c]);
  float ss = x[0] * x[0] + x[1] * x[1] + x[2] * x[2] + x[3] * x[3];
#pragma unroll
  for (int d = 1; d < 64; d <<= 1) ss += __shfl_xor(ss, d);
  const float r = rsqrtf(ss * (1.0f / 256.0f) + 1e-6f);
  float v[4];
#pragma unroll
  for (int c = 0; c < 4; ++c) v[c] = x[c] * r * (1.0f + scale[l * 4 + c]);
  if (ROPE) {
    const float pos = (float)pos_ids[token];
    float o[4];
#pragma unroll
    for (int c = 0; c < 4; ++c) {
      const int j = (l & 31) * 4 + c;
      const float inv_ts = exp2f(-(float)j * 0.10381025296523007f);
      const float arg = pos * inv_ts;
      const float sj = sinf(arg), cj = cosf(arg);
      const float partner = __shfl_xor(v[c], 32);
      o[c] = (l < 32) ? (v[c] * cj - partner * sj) : (v[c] * cj + partner * sj);
    }
#pragma unroll
    for (int c = 0; c < 4; ++c) v[c] = o[c];
  }
  bf16 ob[4];
#pragma unroll
  for (int c = 0; c < 4; ++c) ob[c] = __float2bfloat16(v[c] * mul);
  const size_t doff = ((size_t)((b * nheads + n) * dst_S + dst_t0 + t)) * 256 + l * 4;
  *reinterpret_cast<uint64_t*>(dst + doff) = *reinterpret_cast<uint64_t*>(ob);
}

// ---------------- fused attention (r6 structure, single barrier per tile) ----------------
// 256 blocks (XCD-swizzled), 512 thr / 8 waves; waves 0-3: g=0, waves 4-7: g=1.
// pbuf is wave-private -> mid-tile sync is wave-internal lgkmcnt+sched_barrier only.
__launch_bounds__(512, 2)
__global__ void attn_kernel(const bf16* __restrict__ qb, const bf16* __restrict__ kb,
                            const bf16* __restrict__ vt, bf16* __restrict__ attn_out) {
  __shared__ __align__(16) bf16 Ks[2][64 * 256];   // 32KB each
  __shared__ __align__(16) bf16 Vs[2][256 * 64];   // 32KB each
  __shared__ __align__(16) bf16 pbuf[8][16 * 72];  // rows padded to 144B
  const int lin = blockIdx.x + 16 * blockIdx.y;
  const int kvc = (lin & 7) | (((lin >> 7) & 1) << 3);  // XCD-coherent
  const int qt  = (lin >> 3) & 15;
  const int b = kvc >> 3, kvh = kvc & 7;
  const int tid = threadIdx.x, w = tid >> 6, l = tid & 63;
  const int wq = w & 3, g = w >> 2;
  const int n = kvh * 2 + g;
  const int l15 = l & 15, lhi = l >> 4;
  const int xr = (l15 & 7) << 4;  // frag-read byte swizzle

  const bf16* kbase = kb + (size_t)(b * 8 + kvh) * 2048 * 256;
  const bf16* vbase = vt + (size_t)(b * 8 + kvh) * 256 * 2048;

  const bf16* ksrc[4];
  const bf16* vsrc[4];
#pragma unroll
  for (int i = 0; i < 4; ++i) {
    const int r0 = (w * 4 + i) * 2 + (l >> 5);            // K row 0..63
    const int cbs = ((l & 31) * 16) ^ ((r0 & 7) << 4);    // byte in 512B row
    ksrc[i] = kbase + r0 * 256 + (cbs >> 1);
    const int h0 = (w * 4 + i) * 8 + (l >> 3);            // V row (h) 0..255
    const int cbv = ((l & 7) * 16) ^ ((h0 & 7) << 4);     // byte in 128B row
    vsrc[i] = vbase + (size_t)h0 * 2048 + (cbv >> 1);
  }

  const bf16* qptr = qb + ((size_t)(b * 16 + n) * 1024 + qt * 64 + wq * 16 + l15) * 256 + lhi * 8;
  bv8 qf[8];
#pragma unroll
  for (int f = 0; f < 8; ++f) qf[f] = *reinterpret_cast<const bv8*>(qptr + f * 32);

  f32x4 oacc[16] = {};
  float rs[4] = {0.f, 0.f, 0.f, 0.f};

  const int nt = qt + 17;

#pragma unroll
  for (int i = 0; i < 4; ++i) gload16(ksrc[i], &Ks[0][(w * 4 + i) * 512]);
#pragma unroll
  for (int i = 0; i < 4; ++i) gload16(vsrc[i], &Vs[0][(w * 4 + i) * 512]);
  asm volatile("s_waitcnt vmcnt(0)" ::: "memory");
  __syncthreads();

  for (int it = 0; it < nt; ++it) {
    const int cur = it & 1;
    if (it + 1 < nt) {
      const int itn = it + 1;
      const int s1 = (itn <= qt) ? itn * 64 : 1024 + (itn - qt - 1) * 64;
#pragma unroll
      for (int i = 0; i < 4; ++i)
        gload16(ksrc[i] + (size_t)s1 * 256, &Ks[cur ^ 1][(w * 4 + i) * 512]);
#pragma unroll
      for (int i = 0; i < 4; ++i)
        gload16(vsrc[i] + s1, &Vs[cur ^ 1][(w * 4 + i) * 512]);
    }
    // ---- QK^T from LDS ----
    f32x4 lacc[4] = {};
    __builtin_amdgcn_s_setprio(1);
#pragma unroll
    for (int sub = 0; sub < 4; ++sub) {
      const int rbase = (sub * 16 + l15) * 256;
#pragma unroll
      for (int f = 0; f < 8; ++f) {
        const int off = rbase + (((f * 64 + lhi * 16) ^ xr) >> 1);
        bv8 kf = *reinterpret_cast<const bv8*>(&Ks[cur][off]);
        lacc[sub] = mfma16(qf[f], kf, lacc[sub]);
      }
    }
    __builtin_amdgcn_s_setprio(0);
    // ---- softcap + mask + exp -> wave-private P tile ----
    const bool diag = (it == qt);
#pragma unroll
    for (int sub = 0; sub < 4; ++sub) {
#pragma unroll
      for (int j = 0; j < 4; ++j) {
        const float raw = lacc[sub][j];
        const float e2 = __expf(raw * 0.04f);  // e^(2*raw/50)
        // exp(50*tanh(raw/50)) = exp(50 - 100/(e2+1))
        const bool ok = !diag || (sub * 16 + l15 <= wq * 16 + lhi * 4 + j);
        const float p = ok ? __expf(50.f - __fdividef(100.f, e2 + 1.f)) : 0.f;
        rs[j] += p;
        pbuf[w][(lhi * 4 + j) * 72 + sub * 16 + l15] = __float2bfloat16(p);
      }
    }
    // wave-internal ordering only: pbuf is wave-private (r5-verified construct)
    asm volatile("s_waitcnt lgkmcnt(0)" ::: "memory");
    __builtin_amdgcn_sched_barrier(0);
    // ---- P @ V from LDS ----
    __builtin_amdgcn_s_setprio(1);
#pragma unroll
    for (int ks = 0; ks < 2; ++ks) {
      bv8 pa = *reinterpret_cast<const bv8*>(&pbuf[w][l15 * 72 + ks * 32 + lhi * 8]);
#pragma unroll
      for (int ht = 0; ht < 16; ++ht) {
        const int off = (ht * 16 + l15) * 64 + (((ks * 64 + lhi * 16) ^ xr) >> 1);
        bv8 vf = *reinterpret_cast<const bv8*>(&Vs[cur][off]);
        oacc[ht] = mfma16(pa, vf, oacc[ht]);
      }
    }
    __builtin_amdgcn_s_setprio(0);
    asm volatile("s_waitcnt vmcnt(0)" ::: "memory");  // staged tile landed
    __syncthreads();  // K/V buffer reads done block-wide; next iter may overwrite
  }
  // normalize and store
  float invr[4];
#pragma unroll
  for (int j = 0; j < 4; ++j) {
    float s = rs[j];
    s += __shfl_xor(s, 1);
    s += __shfl_xor(s, 2);
    s += __shfl_xor(s, 4);
    s += __shfl_xor(s, 8);
    invr[j] = 1.0f / s;
  }
  bf16* op = attn_out + ((size_t)(b * 1024 + qt * 64 + wq * 16 + lhi * 4) * 4096) + n * 256 + l15;
#pragma unroll
  for (int ht = 0; ht < 16; ++ht)
#pragma unroll
    for (int j = 0; j < 4; ++j)
      op[(size_t)j * 4096 + ht * 16] = __float2bfloat16(oacc[ht][j] * invr[j]);
}

// ---------------- host launcher ----------------
extern "C" void kernel_launch(void* const* d_in, const int* in_sizes, int n_in,
                              void* d_out, int out_size, void* d_ws, size_t ws_size,
                              hipStream_t stream) {
  (void)in_sizes; (void)n_in; (void)out_size; (void)ws_size;
  const float* hidden = (const float*)d_in[0];
  const float* enc    = (const float*)d_in[1];
  const int*   pos    = (const int*)d_in[2];
  // d_in[3] = merged_attention_mask: deterministic (causal|ones) -> computed analytically
  const float* q_w = (const float*)d_in[4];
  const float* k_w = (const float*)d_in[5];
  const float* v_w = (const float*)d_in[6];
  const float* o_w = (const float*)d_in[7];
  const float* q_s = (const float*)d_in[8];
  const float* k_s = (const float*)d_in[9];
  float* out = (float*)d_out;

  // workspace layout (117,440,512 bytes), write-before-read aliasing (single stream):
  char* base = (char*)d_ws;
  bf16* hid_b  = (bf16*)(base + 0);          // [2048][2048]
  bf16* enc_b  = (bf16*)(base + 8388608);    // [2048][2048]
  bf16* qb     = (bf16*)(base + 0);          // [2][16][1024][256]
  bf16* wqkvt  = (bf16*)(base + 16777216);   // [8192][2048] = qwt|kwt|vwt
  bf16* kbuf   = (bf16*)(base + 16777216);   // [2][8][2048][256]
  bf16* vtb    = (bf16*)(base + 33554432);   // [2][8][256][2048]
  bf16* owt    = (bf16*)(base + 50331648);   // [2048][4096]
  bf16* cself  = (bf16*)(base + 67108864);   // [2048][8192] = q|k_self|v_self
  bf16* attn_b = (bf16*)(base + 67108864);   // [2048][4096]
  float* p1    = (float*)(base + 83886080);  // [2048][2048] f32 split-K partial
  bf16* ccross = (bf16*)(base + 100663296);  // [2048][4096] = k_cross|v_cross

  dim3 tb32(32, 8);
  cast2_f32_bf16<<<8192, 256, 0, stream>>>(hidden, enc, hid_b, enc_b, 1048576);
  transpose_cast_qkv<<<dim3(8, 64, 32), tb32, 0, stream>>>(q_w, k_w, v_w, wqkvt);
  transpose_cast<<<dim3(64, 128, 1), tb32, 0, stream>>>(o_w, owt, 4096, 2048);
  gemm_proj<<<dim3(96, 16), 256, 0, stream>>>(hid_b, enc_b, wqkvt, cself, ccross);
  norm_finalize<true><<<8192, 256, 0, stream>>>(cself, 8192, 0, q_s, pos, qb, 16, 1024, 0, 0.0625f);
  norm_finalize<true><<<4096, 256, 0, stream>>>(cself, 8192, 4096, k_s, pos, kbuf, 8, 2048, 0, 1.0f);
  norm_finalize<false><<<4096, 256, 0, stream>>>(ccross, 4096, 0, k_s, nullptr, kbuf, 8, 2048, 1024, 1.0f);
  transpose_v2<<<dim3(8, 32, 32), tb32, 0, stream>>>(cself + 6144, ccross + 2048, vtb);
  attn_kernel<<<dim3(16, 16), 512, 0, stream>>>(qb, kbuf, vtb, attn_b);
  gemm_osplit<<<dim3(16, 16, 2), 256, 0, stream>>>(attn_b, owt, out, p1);
  add_inplace<<<4096, 256, 0, stream>>>(out, p1, 1048576);
}

// Round 8
// 370.028 us; speedup vs baseline: 1.7575x; 1.0172x over previous
//
#include <hip/hip_runtime.h>
#include <hip/hip_bf16.h>
#include <stdint.h>

typedef __hip_bfloat16 bf16;
typedef __attribute__((ext_vector_type(8))) short bv8;    // 8 x bf16 (mfma A/B frag)
typedef __attribute__((ext_vector_type(4))) float f32x4;  // mfma C/D frag

// Problem constants: B=2, T=1024, S_ENC=1024, D=2048, NQ=16, NKV=8, H=256, SKV=2048

__device__ __forceinline__ f32x4 mfma16(bv8 a, bv8 b, f32x4 c) {
  return __builtin_amdgcn_mfma_f32_16x16x32_bf16(a, b, c, 0, 0, 0);
}

__device__ __forceinline__ void gload16(const void* g, void* lds) {
  __builtin_amdgcn_global_load_lds((const __attribute__((address_space(1))) void*)g,
                                   (__attribute__((address_space(3))) void*)lds, 16, 0, 0);
}

__device__ __forceinline__ void storeC(float* p, float v) { *p = v; }
__device__ __forceinline__ void storeC(bf16* p, float v) { *p = __float2bfloat16(v); }

// ---------------- merged elementwise f32 -> bf16 (both activations, 1 launch) ----------------
__global__ void cast2_f32_bf16(const float* __restrict__ a, const float* __restrict__ b,
                               bf16* __restrict__ da, bf16* __restrict__ db, int n4each) {
  int i = blockIdx.x * blockDim.x + threadIdx.x;
  const float* s;
  bf16* d;
  if (i < n4each) { s = a; d = da; }
  else            { s = b; d = db; i -= n4each; }
  float4 v = reinterpret_cast<const float4*>(s)[i];
  bf16 t[4] = {__float2bfloat16(v.x), __float2bfloat16(v.y),
               __float2bfloat16(v.z), __float2bfloat16(v.w)};
  reinterpret_cast<uint64_t*>(d)[i] = *reinterpret_cast<uint64_t*>(t);
}

// ------- merged QKV weight transpose+cast: 32 head-slices [2048][256] -> [256][2048] -------
__global__ void transpose_cast_qkv(const float* __restrict__ q_w, const float* __restrict__ k_w,
                                   const float* __restrict__ v_w, bf16* __restrict__ dst) {
  __shared__ float tile[32][33];
  const int z = blockIdx.z;
  const float* s = (z < 16) ? q_w + (size_t)z * 524288
                 : (z < 24) ? k_w + (size_t)(z - 16) * 524288
                            : v_w + (size_t)(z - 24) * 524288;
  bf16* d = dst + (size_t)z * 524288;
  const int R = 2048, C = 256;
  const int c0 = blockIdx.x * 32, r0 = blockIdx.y * 32;
  const int x = threadIdx.x, y = threadIdx.y;
#pragma unroll
  for (int i = 0; i < 32; i += 8)
    tile[y + i][x] = s[(size_t)(r0 + y + i) * C + c0 + x];
  __syncthreads();
#pragma unroll
  for (int i = 0; i < 32; i += 8)
    d[(size_t)(c0 + y + i) * R + r0 + x] = __float2bfloat16(tile[x][y + i]);
}

// ------- O-weight transpose+cast: [4096][2048] -> [2048][4096] -------
__global__ void transpose_cast(const float* __restrict__ src, bf16* __restrict__ dst,
                               int R, int C) {
  __shared__ float tile[32][33];
  const float* s = src;
  bf16* d = dst;
  const int c0 = blockIdx.x * 32, r0 = blockIdx.y * 32;
  const int x = threadIdx.x, y = threadIdx.y;
#pragma unroll
  for (int i = 0; i < 32; i += 8)
    tile[y + i][x] = s[(size_t)(r0 + y + i) * C + c0 + x];
  __syncthreads();
#pragma unroll
  for (int i = 0; i < 32; i += 8)
    d[(size_t)(c0 + y + i) * R + r0 + x] = __float2bfloat16(tile[x][y + i]);
}

// ------- merged V transpose: z<16 self (ld 8192, t0=0), else cross (ld 4096, t0=1024) -------
__global__ void transpose_v2(const bf16* __restrict__ vself, const bf16* __restrict__ vcross,
                             bf16* __restrict__ dst) {
  __shared__ bf16 tile[32][33];
  const int z = blockIdx.z;
  const int zz = z & 15, b = zz >> 3, kvh = zz & 7;
  const bool cross = z >= 16;
  const bf16* srcb = cross ? vcross : vself;
  const int src_ld = cross ? 4096 : 8192;
  const int t0 = cross ? 1024 : 0;
  const bf16* s = srcb + (size_t)(b * 1024) * src_ld + kvh * 256;
  bf16* d = dst + (size_t)(zz * 256) * 2048 + t0;
  const int h0 = blockIdx.x * 32, tt0 = blockIdx.y * 32;
  const int x = threadIdx.x, y = threadIdx.y;
#pragma unroll
  for (int i = 0; i < 32; i += 8)
    tile[y + i][x] = s[(size_t)(tt0 + y + i) * src_ld + h0 + x];
  __syncthreads();
#pragma unroll
  for (int i = 0; i < 32; i += 8)
    d[(size_t)(h0 + y + i) * 2048 + tt0 + x] = tile[x][y + i];
}

// ---------------- GEMM body: C[M][N] = A[M][K] * Bt[N][K]^T (m97 128x128, BK=32) ----------------
template <typename CT>
__device__ __forceinline__ void gemm_body(const bf16* __restrict__ A, const bf16* __restrict__ Bt,
                                          CT* __restrict__ C, int N, int K,
                                          int m0, int n0, int kbase, int ksteps) {
  __shared__ __align__(16) bf16 As[128 * 32];
  __shared__ __align__(16) bf16 Bs[128 * 32];
  const int tid = threadIdx.x;
  const int w = tid >> 6, l = tid & 63;
  const int wr = w >> 1, wc = w & 1;
  const int l15 = l & 15, lhi = l >> 4;
  const bf16* ag = A + (size_t)(m0 + (tid >> 2)) * K + kbase + (tid & 3) * 8;
  const bf16* bg = Bt + (size_t)(n0 + (tid >> 2)) * K + kbase + (tid & 3) * 8;
  bf16* asw = As + w * 512;
  bf16* bsw = Bs + w * 512;
  f32x4 acc[4][4] = {};
  for (int k0 = 0; k0 < ksteps; k0 += 32) {
    gload16(ag + k0, asw);
    gload16(ag + (size_t)64 * K + k0, asw + 2048);
    gload16(bg + k0, bsw);
    gload16(bg + (size_t)64 * K + k0, bsw + 2048);
    asm volatile("s_waitcnt vmcnt(0)" ::: "memory");
    __syncthreads();
    bv8 af[4], bfv[4];
#pragma unroll
    for (int m = 0; m < 4; ++m)
      af[m] = *reinterpret_cast<const bv8*>(As + (wr * 64 + m * 16 + l15) * 32 + lhi * 8);
#pragma unroll
    for (int n = 0; n < 4; ++n)
      bfv[n] = *reinterpret_cast<const bv8*>(Bs + (wc * 64 + n * 16 + l15) * 32 + lhi * 8);
#pragma unroll
    for (int m = 0; m < 4; ++m)
#pragma unroll
      for (int n = 0; n < 4; ++n)
        acc[m][n] = mfma16(af[m], bfv[n], acc[m][n]);
    __syncthreads();
  }
  const int r0 = m0 + wr * 64 + lhi * 4;
  const int c0 = n0 + wc * 64 + l15;
#pragma unroll
  for (int m = 0; m < 4; ++m)
#pragma unroll
    for (int n = 0; n < 4; ++n) {
      f32x4 v = acc[m][n];
#pragma unroll
      for (int j = 0; j < 4; ++j)
        storeC(&C[(size_t)(r0 + m * 16 + j) * N + c0 + n * 16], v[j]);
    }
}

// merged self+cross projection GEMM: bx<64 -> self (N=8192), else cross (N=4096)
__launch_bounds__(256)
__global__ void gemm_proj(const bf16* __restrict__ hid, const bf16* __restrict__ enc,
                          const bf16* __restrict__ wqkvt, bf16* __restrict__ cself,
                          bf16* __restrict__ ccross) {
  const int bx = blockIdx.x;
  const bool cross = bx >= 64;
  const bf16* A = cross ? enc : hid;
  const bf16* Bt = cross ? wqkvt + 8388608 : wqkvt;
  bf16* C = cross ? ccross : cself;
  const int N = cross ? 4096 : 8192;
  const int n0 = (cross ? bx - 64 : bx) * 128;
  gemm_body<bf16>(A, Bt, C, N, 2048, blockIdx.y * 128, n0, 0, 2048);
}

// O-projection with split-K=2: z=0 -> out, z=1 -> partial p1 (both f32 [2048][2048])
__launch_bounds__(256)
__global__ void gemm_osplit(const bf16* __restrict__ A, const bf16* __restrict__ Bt,
                            float* __restrict__ out, float* __restrict__ p1) {
  float* C = blockIdx.z ? p1 : out;
  gemm_body<float>(A, Bt, C, 2048, 4096, blockIdx.y * 128, blockIdx.x * 128,
                   blockIdx.z * 2048, 2048);
}

// combine: out += p1 (float4)
__global__ void add_inplace(float* __restrict__ out, const float* __restrict__ p1, int n4) {
  int i = blockIdx.x * blockDim.x + threadIdx.x;
  if (i >= n4) return;
  float4 a = reinterpret_cast<float4*>(out)[i];
  float4 b = reinterpret_cast<const float4*>(p1)[i];
  a.x += b.x; a.y += b.y; a.z += b.z; a.w += b.w;
  reinterpret_cast<float4*>(out)[i] = a;
}

// ---------------- RMSNorm (+optional RoPE) + scale ----------------
template <bool ROPE>
__launch_bounds__(256)
__global__ void norm_finalize(const bf16* __restrict__ src, int src_ld, int src_col0,
                              const float* __restrict__ scale,
                              const int* __restrict__ pos_ids,
                              bf16* __restrict__ dst, int nheads, int dst_S, int dst_t0,
                              float mul) {
  const int gid = blockIdx.x * 4 + (threadIdx.x >> 6);
  const int l = threadIdx.x & 63;
  const int token = gid / nheads;
  const int n = gid - token * nheads;
  const int b = token >> 10;
  const int t = token & 1023;
  const size_t soff = (size_t)token * src_ld + src_col0 + n * 256 + l * 4;
  bf16 xb[4];
  *reinterpret_cast<uint64_t*>(xb) = *reinterpret_cast<const uint64_t*>(src + soff);
  float x[4];
#pragma unroll
  for (int c = 0; c < 4; ++c) x[c] = __bfloat162float(xb[c]);
  float ss = x[0] * x[0] + x[1] * x[1] + x[2] * x[2] + x[3] * x[3];
#pragma unroll
  for (int d = 1; d < 64; d <<= 1) ss += __shfl_xor(ss, d);
  const float r = rsqrtf(ss * (1.0f / 256.0f) + 1e-6f);
  float v[4];
#pragma unroll
  for (int c = 0; c < 4; ++c) v[c] = x[c] * r * (1.0f + scale[l * 4 + c]);
  if (ROPE) {
    const float pos = (float)pos_ids[token];
    float o[4];
#pragma unroll
    for (int c = 0; c < 4; ++c) {
      const int j = (l & 31) * 4 + c;
      const float inv_ts = exp2f(-(float)j * 0.10381025296523007f);
      const float arg = pos * inv_ts;
      const float sj = sinf(arg), cj = cosf(arg);
      const float partner = __shfl_xor(v[c], 32);
      o[c] = (l < 32) ? (v[c] * cj - partner * sj) : (v[c] * cj + partner * sj);
    }
#pragma unroll
    for (int c = 0; c < 4; ++c) v[c] = o[c];
  }
  bf16 ob[4];
#pragma unroll
  for (int c = 0; c < 4; ++c) ob[c] = __float2bfloat16(v[c] * mul);
  const size_t doff = ((size_t)((b * nheads + n) * dst_S + dst_t0 + t)) * 256 + l * 4;
  *reinterpret_cast<uint64_t*>(dst + doff) = *reinterpret_cast<uint64_t*>(ob);
}

// ---------------- fused attention (split-role waves: halved LDS read volume) ----------------
// 256 blocks (XCD-swizzled), 512 thr / 8 waves, q-block 64, both heads per block.
// QK^T role: wave (g=w>>2, qsp=(w>>1)&1, sh=w&1): 2 q-subtiles x 2 s-subtiles
//   -> 16 K-frag reads, 32 MFMAs (vs r7: 32 reads).
// PV   role: wave (g=w>>2, hq=w&3): all 4 q-subtiles x 4 ht (64 h cols)
//   -> 8 V-frag + 8 P-frag reads, 32 MFMAs (vs r7: 34 reads).
// P crosses waves within a g-group -> mid-tile __syncthreads (measured ~free, r7).
// Per-CU LDS reads/tile: 512 -> 256 b128. MFMA work unchanged.
__launch_bounds__(512, 2)
__global__ void attn_kernel(const bf16* __restrict__ qb, const bf16* __restrict__ kb,
                            const bf16* __restrict__ vt, bf16* __restrict__ attn_out) {
  __shared__ __align__(16) bf16 Ks[2][64 * 256];   // 32KB each
  __shared__ __align__(16) bf16 Vs[2][256 * 64];   // 32KB each
  __shared__ __align__(16) bf16 pbuf[2][64 * 72];  // [g][64 q][72 pad]
  __shared__ float rsb[2][2][2][2][4][4];          // [g][qsp][sh][qs2][j][lhi]
  const int lin = blockIdx.x + 16 * blockIdx.y;
  const int kvc = (lin & 7) | (((lin >> 7) & 1) << 3);  // XCD-coherent
  const int qt  = (lin >> 3) & 15;
  const int b = kvc >> 3, kvh = kvc & 7;
  const int tid = threadIdx.x, w = tid >> 6, l = tid & 63;
  const int g = w >> 2, qsp = (w >> 1) & 1, sh = w & 1, hq = w & 3;
  const int n = kvh * 2 + g;
  const int l15 = l & 15, lhi = l >> 4;
  const int xr = (l15 & 7) << 4;  // frag-read byte swizzle

  const bf16* kbase = kb + (size_t)(b * 8 + kvh) * 2048 * 256;
  const bf16* vbase = vt + (size_t)(b * 8 + kvh) * 256 * 2048;

  // staging sources (identical to r7; thread t covers LDS bytes [16t,16t+16))
  const bf16* ksrc[4];
  const bf16* vsrc[4];
#pragma unroll
  for (int i = 0; i < 4; ++i) {
    const int r0 = (w * 4 + i) * 2 + (l >> 5);            // K row 0..63
    const int cbs = ((l & 31) * 16) ^ ((r0 & 7) << 4);    // byte in 512B row
    ksrc[i] = kbase + r0 * 256 + (cbs >> 1);
    const int h0 = (w * 4 + i) * 8 + (l >> 3);            // V row (h) 0..255
    const int cbv = ((l & 7) * 16) ^ ((h0 & 7) << 4);     // byte in 128B row
    vsrc[i] = vbase + (size_t)h0 * 2048 + (cbv >> 1);
  }

  // Q fragments for this wave's 2 q-subtiles (head n), register-resident
  bv8 qf[2][8];
#pragma unroll
  for (int qs2 = 0; qs2 < 2; ++qs2) {
    const bf16* qp = qb + ((size_t)(b * 16 + n) * 1024 + qt * 64 +
                           (qsp * 2 + qs2) * 16 + l15) * 256 + lhi * 8;
#pragma unroll
    for (int f = 0; f < 8; ++f) qf[qs2][f] = *reinterpret_cast<const bv8*>(qp + f * 32);
  }

  f32x4 oacc[4][4] = {};  // [qs][i] -> O rows qs*16+lhi*4+j, cols (hq*4+i)*16+l15
  float rs[2][4] = {};

  const int nt = qt + 17;

#pragma unroll
  for (int i = 0; i < 4; ++i) gload16(ksrc[i], &Ks[0][(w * 4 + i) * 512]);
#pragma unroll
  for (int i = 0; i < 4; ++i) gload16(vsrc[i], &Vs[0][(w * 4 + i) * 512]);
  asm volatile("s_waitcnt vmcnt(0)" ::: "memory");
  __syncthreads();

  for (int it = 0; it < nt; ++it) {
    const int cur = it & 1;
    if (it + 1 < nt) {  // prefetch next tile into other buffer
      const int itn = it + 1;
      const int s1 = (itn <= qt) ? itn * 64 : 1024 + (itn - qt - 1) * 64;
#pragma unroll
      for (int i = 0; i < 4; ++i)
        gload16(ksrc[i] + (size_t)s1 * 256, &Ks[cur ^ 1][(w * 4 + i) * 512]);
#pragma unroll
      for (int i = 0; i < 4; ++i)
        gload16(vsrc[i] + s1, &Vs[cur ^ 1][(w * 4 + i) * 512]);
    }
    // ---- QK^T: this wave's 2 s-subtiles x 2 q-subtiles ----
    f32x4 lacc[2][2] = {};  // [qs2][ss2]
    __builtin_amdgcn_s_setprio(1);
#pragma unroll
    for (int ss2 = 0; ss2 < 2; ++ss2) {
      const int rbase = ((sh * 2 + ss2) * 16 + l15) * 256;
#pragma unroll
      for (int f = 0; f < 8; ++f) {
        const int off = rbase + (((f * 64 + lhi * 16) ^ xr) >> 1);
        bv8 kf = *reinterpret_cast<const bv8*>(&Ks[cur][off]);
        lacc[0][ss2] = mfma16(qf[0][f], kf, lacc[0][ss2]);
        lacc[1][ss2] = mfma16(qf[1][f], kf, lacc[1][ss2]);
      }
    }
    __builtin_amdgcn_s_setprio(0);
    // ---- softcap + mask + exp -> P tile (cross-wave within g-group) ----
    const bool diag = (it == qt);
#pragma unroll
    for (int qs2 = 0; qs2 < 2; ++qs2)
#pragma unroll
      for (int ss2 = 0; ss2 < 2; ++ss2)
#pragma unroll
        for (int j = 0; j < 4; ++j) {
          const float raw = lacc[qs2][ss2][j];
          const float e2 = __expf(raw * 0.04f);  // e^(2*raw/50)
          // exp(50*tanh(raw/50)) = exp(50 - 100/(e2+1))
          const bool ok = !diag ||
              ((sh * 2 + ss2) * 16 + l15 <= (qsp * 2 + qs2) * 16 + lhi * 4 + j);
          const float p = ok ? __expf(50.f - __fdividef(100.f, e2 + 1.f)) : 0.f;
          rs[qs2][j] += p;
          pbuf[g][((qsp * 2 + qs2) * 16 + lhi * 4 + j) * 72 + (sh * 2 + ss2) * 16 + l15] =
              __float2bfloat16(p);
        }
    __syncthreads();  // P visible to g-group PV readers
    // ---- PV: this wave's 4 ht x all 4 q-subtiles ----
    __builtin_amdgcn_s_setprio(1);
#pragma unroll
    for (int ks = 0; ks < 2; ++ks) {
      bv8 pa[4];
#pragma unroll
      for (int qs = 0; qs < 4; ++qs)
        pa[qs] = *reinterpret_cast<const bv8*>(&pbuf[g][(qs * 16 + l15) * 72 + ks * 32 + lhi * 8]);
#pragma unroll
      for (int i = 0; i < 4; ++i) {
        const int off = ((hq * 4 + i) * 16 + l15) * 64 + (((ks * 64 + lhi * 16) ^ xr) >> 1);
        bv8 vf = *reinterpret_cast<const bv8*>(&Vs[cur][off]);
#pragma unroll
        for (int qs = 0; qs < 4; ++qs) oacc[qs][i] = mfma16(pa[qs], vf, oacc[qs][i]);
      }
    }
    __builtin_amdgcn_s_setprio(0);
    asm volatile("s_waitcnt vmcnt(0)" ::: "memory");  // staged tile landed
    __syncthreads();  // K/V/pbuf reads done; next iter may overwrite
  }
  // ---- rowsum combine across sh halves, then normalize + store ----
#pragma unroll
  for (int qs2 = 0; qs2 < 2; ++qs2)
#pragma unroll
    for (int j = 0; j < 4; ++j) {
      float s = rs[qs2][j];
      s += __shfl_xor(s, 1);
      s += __shfl_xor(s, 2);
      s += __shfl_xor(s, 4);
      s += __shfl_xor(s, 8);
      if (l15 == 0) rsb[g][qsp][sh][qs2][j][lhi] = s;
    }
  __syncthreads();
  float invr[4][4];
#pragma unroll
  for (int qs = 0; qs < 4; ++qs)
#pragma unroll
    for (int j = 0; j < 4; ++j)
      invr[qs][j] = 1.0f / (rsb[g][qs >> 1][0][qs & 1][j][lhi] +
                            rsb[g][qs >> 1][1][qs & 1][j][lhi]);
  bf16* op = attn_out + ((size_t)(b * 1024 + qt * 64 + lhi * 4) * 4096) + n * 256 + l15;
#pragma unroll
  for (int qs = 0; qs < 4; ++qs)
#pragma unroll
    for (int i = 0; i < 4; ++i)
#pragma unroll
      for (int j = 0; j < 4; ++j)
        op[(size_t)(qs * 16 + j) * 4096 + (hq * 4 + i) * 16] =
            __float2bfloat16(oacc[qs][i][j] * invr[qs][j]);
}

// ---------------- host launcher ----------------
extern "C" void kernel_launch(void* const* d_in, const int* in_sizes, int n_in,
                              void* d_out, int out_size, void* d_ws, size_t ws_size,
                              hipStream_t stream) {
  (void)in_sizes; (void)n_in; (void)out_size; (void)ws_size;
  const float* hidden = (const float*)d_in[0];
  const float* enc    = (const float*)d_in[1];
  const int*   pos    = (const int*)d_in[2];
  // d_in[3] = merged_attention_mask: deterministic (causal|ones) -> computed analytically
  const float* q_w = (const float*)d_in[4];
  const float* k_w = (const float*)d_in[5];
  const float* v_w = (const float*)d_in[6];
  const float* o_w = (const float*)d_in[7];
  const float* q_s = (const float*)d_in[8];
  const float* k_s = (const float*)d_in[9];
  float* out = (float*)d_out;

  // workspace layout (117,440,512 bytes), write-before-read aliasing (single stream):
  char* base = (char*)d_ws;
  bf16* hid_b  = (bf16*)(base + 0);          // [2048][2048]
  bf16* enc_b  = (bf16*)(base + 8388608);    // [2048][2048]
  bf16* qb     = (bf16*)(base + 0);          // [2][16][1024][256]
  bf16* wqkvt  = (bf16*)(base + 16777216);   // [8192][2048] = qwt|kwt|vwt
  bf16* kbuf   = (bf16*)(base + 16777216);   // [2][8][2048][256]
  bf16* vtb    = (bf16*)(base + 33554432);   // [2][8][256][2048]
  bf16* owt    = (bf16*)(base + 50331648);   // [2048][4096]
  bf16* cself  = (bf16*)(base + 67108864);   // [2048][8192] = q|k_self|v_self
  bf16* attn_b = (bf16*)(base + 67108864);   // [2048][4096]
  float* p1    = (float*)(base + 83886080);  // [2048][2048] f32 split-K partial
  bf16* ccross = (bf16*)(base + 100663296);  // [2048][4096] = k_cross|v_cross

  dim3 tb32(32, 8);
  cast2_f32_bf16<<<8192, 256, 0, stream>>>(hidden, enc, hid_b, enc_b, 1048576);
  transpose_cast_qkv<<<dim3(8, 64, 32), tb32, 0, stream>>>(q_w, k_w, v_w, wqkvt);
  transpose_cast<<<dim3(64, 128, 1), tb32, 0, stream>>>(o_w, owt, 4096, 2048);
  gemm_proj<<<dim3(96, 16), 256, 0, stream>>>(hid_b, enc_b, wqkvt, cself, ccross);
  norm_finalize<true><<<8192, 256, 0, stream>>>(cself, 8192, 0, q_s, pos, qb, 16, 1024, 0, 0.0625f);
  norm_finalize<true><<<4096, 256, 0, stream>>>(cself, 8192, 4096, k_s, pos, kbuf, 8, 2048, 0, 1.0f);
  norm_finalize<false><<<4096, 256, 0, stream>>>(ccross, 4096, 0, k_s, nullptr, kbuf, 8, 2048, 1024, 1.0f);
  transpose_v2<<<dim3(8, 32, 32), tb32, 0, stream>>>(cself + 6144, ccross + 2048, vtb);
  attn_kernel<<<dim3(16, 16), 512, 0, stream>>>(qb, kbuf, vtb, attn_b);
  gemm_osplit<<<dim3(16, 16, 2), 256, 0, stream>>>(attn_b, owt, out, p1);
  add_inplace<<<4096, 256, 0, stream>>>(out, p1, 1048576);
}